// Round 8
// baseline (566.184 us; speedup 1.0000x reference)
//
#include <hip/hip_runtime.h>

// ---------------------------------------------------------------------------
// Hetero GraphSAGE (user<->movie). Bucketed CSR build, bf16 gather tables,
// register-tiled GEMMs, layer-2 project-before-aggregate (z-trick).
// ---------------------------------------------------------------------------

constexpr int NU = 100000;   // users
constexpr int NM = 50000;    // movies
constexpr int NE = 4000000;  // edges
constexpr int FU = 24;       // user feat
constexpr int FM = 404;      // movie feat
constexpr int HD = 64;       // hidden

constexpr int BSH = 8;                       // bucket = 256 node ids
constexpr int MBK = (NM + 255) >> BSH;       // 196 movie buckets
constexpr int UBK = (NU + 255) >> BSH;       // 391 user buckets
constexpr int NBK = MBK + UBK;               // 587
constexpr int EPB = 8192;                    // edges per passA block

static inline size_t alignup(size_t x) { return (x + 255) & ~size_t(255); }

__device__ __forceinline__ float bf2f(unsigned short h) {
  return __uint_as_float(((unsigned int)h) << 16);
}
__device__ __forceinline__ unsigned short f2bf(float f) {
  unsigned int u = __float_as_uint(f);
  u = (u + 0x7FFFu + ((u >> 16) & 1u)) >> 16;   // RNE
  return (unsigned short)u;
}
__device__ __forceinline__ float2 unpk(unsigned u) {
  return make_float2(__uint_as_float(u << 16), __uint_as_float(u & 0xFFFF0000u));
}

// ---------------- CSR build ----------------

__global__ __launch_bounds__(256) void histB_kernel(const int* __restrict__ src,
                                                    const int* __restrict__ dst,
                                                    int* __restrict__ bh) {
  __shared__ int h[NBK];
  for (int i = threadIdx.x; i < NBK; i += 256) h[i] = 0;
  __syncthreads();
  int idx = blockIdx.x * 256 + threadIdx.x;
  int stride = gridDim.x * 256;
  for (int i = idx; i < NE; i += stride) {
    atomicAdd(&h[dst[i] >> BSH], 1);
    atomicAdd(&h[MBK + (src[i] >> BSH)], 1);
  }
  __syncthreads();
  for (int i = threadIdx.x; i < NBK; i += 256) {
    int c = h[i];
    if (c) atomicAdd(&bh[i], c);
  }
}

__global__ __launch_bounds__(1024) void scanB_kernel(const int* __restrict__ bh,
                                                     int* __restrict__ bbase_m,
                                                     int* __restrict__ bbase_u,
                                                     int* __restrict__ bcur_m,
                                                     int* __restrict__ bcur_u) {
  __shared__ int tmp[1024];
  int t = threadIdx.x;
  int vm = (t < MBK) ? bh[t] : 0;
  tmp[t] = vm;
  __syncthreads();
  for (int off = 1; off < 1024; off <<= 1) {
    int v = (t >= off) ? tmp[t - off] : 0;
    __syncthreads();
    tmp[t] += v;
    __syncthreads();
  }
  if (t < MBK) {
    int e = tmp[t] - vm;
    bbase_m[t] = e; bcur_m[t] = e;
    if (t == MBK - 1) bbase_m[MBK] = tmp[t];
  }
  __syncthreads();
  int vu = (t < UBK) ? bh[MBK + t] : 0;
  tmp[t] = vu;
  __syncthreads();
  for (int off = 1; off < 1024; off <<= 1) {
    int v = (t >= off) ? tmp[t - off] : 0;
    __syncthreads();
    tmp[t] += v;
    __syncthreads();
  }
  if (t < UBK) {
    int e = tmp[t] - vu;
    bbase_u[t] = e; bcur_u[t] = e;
    if (t == UBK - 1) bbase_u[UBK] = tmp[t];
  }
}

__global__ __launch_bounds__(1024) void passA_kernel(
    const int* __restrict__ src, const int* __restrict__ dst,
    int* __restrict__ bcur_m, int* __restrict__ bcur_u,
    unsigned* __restrict__ stage_m, unsigned* __restrict__ stage_u) {
  __shared__ int hB[NBK];
  int t = threadIdx.x;
  for (int i = t; i < NBK; i += 1024) hB[i] = 0;
  __syncthreads();
  int e0 = blockIdx.x * EPB + t;
  int sv[8], dv[8], rm[8], ru[8];
#pragma unroll
  for (int k = 0; k < 8; ++k) {
    int e = e0 + k * 1024;
    if (e < NE) {
      int s = src[e], d = dst[e];
      sv[k] = s; dv[k] = d;
      rm[k] = atomicAdd(&hB[d >> BSH], 1);
      ru[k] = atomicAdd(&hB[MBK + (s >> BSH)], 1);
    } else {
      sv[k] = -1;
    }
  }
  __syncthreads();
  for (int i = t; i < NBK; i += 1024) {
    int c = hB[i];
    int base = 0;
    if (c) base = (i < MBK) ? atomicAdd(&bcur_m[i], c) : atomicAdd(&bcur_u[i - MBK], c);
    hB[i] = base;
  }
  __syncthreads();
#pragma unroll
  for (int k = 0; k < 8; ++k) {
    if (sv[k] >= 0) {
      int s = sv[k], d = dv[k];
      stage_m[hB[d >> BSH] + rm[k]] = ((unsigned)(d & 255) << 24) | (unsigned)s;
      stage_u[hB[MBK + (s >> BSH)] + ru[k]] = ((unsigned)(s & 255) << 24) | (unsigned)d;
    }
  }
}

__global__ __launch_bounds__(1024) void passB_kernel(
    const int* __restrict__ bbase_m, const int* __restrict__ bbase_u,
    const unsigned* __restrict__ stage_m, const unsigned* __restrict__ stage_u,
    int* __restrict__ csr_m, int* __restrict__ csr_u,
    int* __restrict__ rp_m, int* __restrict__ rp_u) {
  __shared__ int cnt[256];
  __shared__ int sc[256];
  int b = blockIdx.x;
  const unsigned* stage; int* csr; int* rp; int idbase, ntot, bb, be;
  if (b < MBK) {
    stage = stage_m; csr = csr_m; rp = rp_m;
    idbase = b << BSH; ntot = NM;
    bb = bbase_m[b]; be = bbase_m[b + 1];
  } else {
    int c = b - MBK;
    stage = stage_u; csr = csr_u; rp = rp_u;
    idbase = c << BSH; ntot = NU;
    bb = bbase_u[c]; be = bbase_u[c + 1];
  }
  int nloc = min(256, ntot - idbase);
  int t = threadIdx.x;
  if (t < 256) cnt[t] = 0;
  __syncthreads();
  for (int j = bb + t; j < be; j += 1024) atomicAdd(&cnt[stage[j] >> 24], 1);
  __syncthreads();
  int c0 = (t < 256) ? cnt[t] : 0;
  if (t < 256) sc[t] = c0;
  __syncthreads();
  for (int off = 1; off < 256; off <<= 1) {
    int v = 0;
    if (t < 256 && t >= off) v = sc[t - off];
    __syncthreads();
    if (t < 256) sc[t] += v;
    __syncthreads();
  }
  if (t < nloc) {
    int e = bb + sc[t] - c0;
    rp[idbase + t] = e;
    cnt[t] = e;                     // reuse as cursor
  }
  if (t == 0 && idbase + nloc == ntot) rp[ntot] = be;
  __syncthreads();
  for (int j = bb + t; j < be; j += 1024) {
    unsigned e = stage[j];
    int pos = atomicAdd(&cnt[e >> 24], 1);
    csr[pos] = (int)(e & 0xFFFFFFu);
  }
}

// ---------------- input projections (write bf16 tables) ----------------

__global__ void proj_user_kernel(const float* __restrict__ xu, const float* __restrict__ Wu,
                                 const float* __restrict__ bu, unsigned short* __restrict__ hu) {
  __shared__ float Wt[FU][HD + 1];
  __shared__ float Xl[16][FU];
  int t = threadIdx.x;
  int lane = t & 63, wg = t >> 6;
  int row0 = blockIdx.x * 16;
  for (int h = wg; h < HD; h += 4)
    if (lane < FU) Wt[lane][h] = Wu[h * FU + lane];
  for (int r = wg; r < 16; r += 4)
    if (lane < FU) Xl[r][lane] = xu[(row0 + r) * FU + lane];
  __syncthreads();
  float b = bu[lane];
  float acc[4] = {0.f, 0.f, 0.f, 0.f};
  for (int k = 0; k < FU; ++k) {
    float w = Wt[k][lane];
#pragma unroll
    for (int j = 0; j < 4; ++j) acc[j] += Xl[wg * 4 + j][k] * w;
  }
#pragma unroll
  for (int j = 0; j < 4; ++j)
    hu[(row0 + wg * 4 + j) * HD + lane] = f2bf(acc[j] + b);
}

// Movie projection: 128x64 block tile, 8x8 thread tile (128 threads),
// K-chunk 32. Per-row XOR swizzle swz(r)=((r>>3)&7)<<2 makes all inner-loop
// b128 reads broadcast/disjoint. 16 b128 reads per 256 FMAs (2 FLOP/B).
__global__ __launch_bounds__(128) void proj_movie_kernel(
    const float* __restrict__ xm, const float* __restrict__ Wm,
    const float* __restrict__ bm, unsigned short* __restrict__ hm) {
  __shared__ float Xs[128][32];
  __shared__ float Ws[64][32];
  int t = threadIdx.x;
  int row0 = blockIdx.x * 128;
  int cg = t & 7;           // col group: cols cg*8..+8
  int rg = (t >> 3) * 8;    // rows rg..rg+8
  int cl = cg * 8;
  int swzX = ((rg >> 3) & 7) << 2;
  int swzW = cg << 2;
  float acc[8][8];
#pragma unroll
  for (int j = 0; j < 8; ++j)
#pragma unroll
    for (int c = 0; c < 8; ++c) acc[j][c] = 0.f;

  for (int k0 = 0; k0 < FM; k0 += 32) {
    int kc = min(32, FM - k0);
    __syncthreads();
    // stage X: 128 rows x 8 float4 groups
    for (int i = t; i < 1024; i += 128) {
      int r = i >> 3, c4 = (i & 7) * 4;
      float4 v = make_float4(0.f, 0.f, 0.f, 0.f);
      if (row0 + r < NM && c4 < kc)
        v = *(const float4*)(xm + (size_t)(row0 + r) * FM + k0 + c4);
      *(float4*)&Xs[r][c4 ^ (((r >> 3) & 7) << 2)] = v;
    }
    // stage W: 64 rows x 8 float4 groups
    for (int i = t; i < 512; i += 128) {
      int h = i >> 3, c4 = (i & 7) * 4;
      float4 v = make_float4(0.f, 0.f, 0.f, 0.f);
      if (c4 < kc)
        v = *(const float4*)(Wm + (size_t)h * FM + k0 + c4);
      *(float4*)&Ws[h][c4 ^ (((h >> 3) & 7) << 2)] = v;
    }
    __syncthreads();
#pragma unroll
    for (int kk = 0; kk < 32; kk += 4) {
      float4 xv[8];
#pragma unroll
      for (int j = 0; j < 8; ++j)
        xv[j] = *(const float4*)&Xs[rg + j][kk ^ swzX];
#pragma unroll
      for (int c = 0; c < 8; ++c) {
        float4 wv = *(const float4*)&Ws[cl + c][kk ^ swzW];
#pragma unroll
        for (int j = 0; j < 8; ++j)
          acc[j][c] += xv[j].x * wv.x + xv[j].y * wv.y + xv[j].z * wv.z + xv[j].w * wv.w;
      }
    }
  }
  float bv[8];
#pragma unroll
  for (int c = 0; c < 8; ++c) bv[c] = bm[cl + c];
#pragma unroll
  for (int j = 0; j < 8; ++j) {
    int row = row0 + rg + j;
    if (row < NM) {
      uint4 o;
      o.x = (unsigned)f2bf(acc[j][0] + bv[0]) | ((unsigned)f2bf(acc[j][1] + bv[1]) << 16);
      o.y = (unsigned)f2bf(acc[j][2] + bv[2]) | ((unsigned)f2bf(acc[j][3] + bv[3]) << 16);
      o.z = (unsigned)f2bf(acc[j][4] + bv[4]) | ((unsigned)f2bf(acc[j][5] + bv[5]) << 16);
      o.w = (unsigned)f2bf(acc[j][6] + bv[6]) | ((unsigned)f2bf(acc[j][7] + bv[7]) << 16);
      *(uint4*)(hm + (size_t)row * HD + cl) = o;
    }
  }
}

// ---------------- mean aggregation: 4 neighbors/wave, 8B/lane gathers ------

__global__ __launch_bounds__(256) void agg_mean_kernel(
    const unsigned short* __restrict__ table, const int* __restrict__ rp,
    const int* __restrict__ csr, float* __restrict__ out, int n) {
  int wid = threadIdx.x >> 6;
  int lane = threadIdx.x & 63;
  int row = blockIdx.x * 4 + wid;
  if (row >= n) return;
  int beg = rp[row], end = rp[row + 1];
  int g = lane >> 4;        // neighbor slot 0..3
  int fq = lane & 15;       // feature quad
  float a0 = 0.f, a1 = 0.f, a2 = 0.f, a3 = 0.f;
  int i = beg;
  for (; i + 8 <= end; i += 8) {
    int n0 = csr[i + g];
    int n1 = csr[i + 4 + g];
    uint2 v0 = *(const uint2*)(table + (size_t)n0 * HD + fq * 4);
    uint2 v1 = *(const uint2*)(table + (size_t)n1 * HD + fq * 4);
    float2 p0 = unpk(v0.x), p1 = unpk(v0.y);
    float2 q0 = unpk(v1.x), q1 = unpk(v1.y);
    a0 += p0.x + q0.x; a1 += p0.y + q0.y;
    a2 += p1.x + q1.x; a3 += p1.y + q1.y;
  }
  for (; i < end; i += 4) {
    int idx = i + g;
    if (idx < end) {
      int nb = csr[idx];
      uint2 v = *(const uint2*)(table + (size_t)nb * HD + fq * 4);
      float2 p0 = unpk(v.x), p1 = unpk(v.y);
      a0 += p0.x; a1 += p0.y; a2 += p1.x; a3 += p1.y;
    }
  }
  a0 += __shfl_xor(a0, 16); a0 += __shfl_xor(a0, 32);
  a1 += __shfl_xor(a1, 16); a1 += __shfl_xor(a1, 32);
  a2 += __shfl_xor(a2, 16); a2 += __shfl_xor(a2, 32);
  a3 += __shfl_xor(a3, 16); a3 += __shfl_xor(a3, 32);
  float inv = 1.0f / fmaxf((float)(end - beg), 1.0f);
  if (lane < 16) {
    float4 o = make_float4(a0 * inv, a1 * inv, a2 * inv, a3 * inv);
    *(float4*)(out + (size_t)row * HD + fq * 4) = o;
  }
}

// ---------------- SAGE linear 64->64 + relu (register-tiled) ----------------

template <int OUTBF>
__global__ __launch_bounds__(256, 3) void sage64_kernel(
    const float* __restrict__ agg, const unsigned short* __restrict__ xd,
    const float* __restrict__ Wl, const float* __restrict__ bl,
    const float* __restrict__ Wr, void* __restrict__ outp, int n) {
  __shared__ float Ws[128][65];     // [k][h], padded (scalar reads only)
  __shared__ float Xs[32][128];     // [row][k] : k<64 agg, k>=64 x
  int t = threadIdx.x;
  int lane = t & 63, wid = t >> 6;
  int row0 = blockIdx.x * 32;
  for (int i = t; i < 4096; i += 256) {
    int h = i >> 6, k = i & 63;
    Ws[k][h] = Wl[i];
  }
  for (int i = t; i < 4096; i += 256) {
    int h = i >> 6, k = i & 63;
    Ws[64 + k][h] = Wr[i];
  }
  for (int i = t; i < 512; i += 256) {
    int r = i >> 4, c4 = i & 15;
    if (row0 + r < n) {
      float4 v = ((const float4*)(agg + (size_t)(row0 + r) * HD))[c4];
      *(float4*)&Xs[r][c4 * 4] = v;
    }
  }
  for (int i = t; i < 512; i += 256) {
    int r = i >> 4, c4 = i & 15;
    if (row0 + r < n) {
      uint2 v = ((const uint2*)(xd + (size_t)(row0 + r) * HD))[c4];
      float2 p0 = unpk(v.x), p1 = unpk(v.y);
      *(float4*)&Xs[r][64 + c4 * 4] = make_float4(p0.x, p0.y, p1.x, p1.y);
    }
  }
  __syncthreads();
  float acc[8] = {0.f, 0.f, 0.f, 0.f, 0.f, 0.f, 0.f, 0.f};
  int rbase = wid * 8;
#pragma unroll 4
  for (int k = 0; k < 128; ++k) {
    float wv = Ws[k][lane];
#pragma unroll
    for (int j = 0; j < 8; ++j) acc[j] += Xs[rbase + j][k] * wv;
  }
  float b = bl[lane];
#pragma unroll
  for (int j = 0; j < 8; ++j) {
    int row = row0 + rbase + j;
    if (row < n) {
      float v = fmaxf(acc[j] + b, 0.f);
      if (OUTBF) ((unsigned short*)outp)[(size_t)row * HD + lane] = f2bf(v);
      else       ((float*)outp)[(size_t)row * HD + lane] = v;
    }
  }
}

// ---------------- layer 2 (z-trick): project u1 -> z[NU][4] ----------------

__global__ __launch_bounds__(256) void zproj_kernel(
    const unsigned short* __restrict__ u1, const float* __restrict__ Wl2,
    float4* __restrict__ z) {
  __shared__ float W[3][64];
  int t = threadIdx.x;
  if (t < 192) W[t / 64][t & 63] = Wl2[t];
  __syncthreads();
  int wid = t >> 6, lane = t & 63;
  int g = lane >> 4, fq = lane & 15;
  int row = blockIdx.x * 16 + wid * 4 + g;
  if (row >= NU) return;
  uint2 v = *(const uint2*)(u1 + (size_t)row * HD + fq * 4);
  float2 p0 = unpk(v.x), p1 = unpk(v.y);
  int f = fq * 4;
  float z0 = p0.x * W[0][f] + p0.y * W[0][f + 1] + p1.x * W[0][f + 2] + p1.y * W[0][f + 3];
  float z1 = p0.x * W[1][f] + p0.y * W[1][f + 1] + p1.x * W[1][f + 2] + p1.y * W[1][f + 3];
  float z2 = p0.x * W[2][f] + p0.y * W[2][f + 1] + p1.x * W[2][f + 2] + p1.y * W[2][f + 3];
#pragma unroll
  for (int off = 1; off < 16; off <<= 1) {
    z0 += __shfl_xor(z0, off);
    z1 += __shfl_xor(z1, off);
    z2 += __shfl_xor(z2, off);
  }
  if (fq == 0) z[row] = make_float4(z0, z1, z2, 0.f);
}

// agg4: mean of z over movie neighborhoods. 16B/edge gather (L2-resident).
__global__ __launch_bounds__(256) void agg4_kernel(
    const float4* __restrict__ z, const int* __restrict__ rp,
    const int* __restrict__ csr, float4* __restrict__ zagg, int n) {
  int wid = threadIdx.x >> 6, lane = threadIdx.x & 63;
  int row = blockIdx.x * 4 + wid;
  if (row >= n) return;
  int beg = rp[row], end = rp[row + 1];
  float s0 = 0.f, s1 = 0.f, s2 = 0.f;
  for (int i = beg + lane; i < end; i += 64) {
    float4 v = z[csr[i]];
    s0 += v.x; s1 += v.y; s2 += v.z;
  }
#pragma unroll
  for (int off = 1; off < 64; off <<= 1) {
    s0 += __shfl_xor(s0, off);
    s1 += __shfl_xor(s1, off);
    s2 += __shfl_xor(s2, off);
  }
  if (lane == 0) {
    float inv = 1.0f / fmaxf((float)(end - beg), 1.0f);
    zagg[row] = make_float4(s0 * inv, s1 * inv, s2 * inv, 0.f);
  }
}

// out2: out[m][g] = zagg[m][g] + bl2[g] + m1[m] . Wr2[g]
__global__ void out2_kernel(const float4* __restrict__ zagg, const float* __restrict__ m1,
                            const float* __restrict__ Wr2, const float* __restrict__ bl2,
                            float* __restrict__ out, int n) {
  int wid = threadIdx.x >> 6, lane = threadIdx.x & 63;
  int row = blockIdx.x * 4 + wid;
  if (row >= n) return;
  float mm = m1[(size_t)row * HD + lane];
  float4 za = zagg[row];
  float zc[3] = {za.x, za.y, za.z};
#pragma unroll
  for (int g = 0; g < 3; ++g) {
    float p = mm * Wr2[g * HD + lane];
#pragma unroll
    for (int off = 32; off > 0; off >>= 1) p += __shfl_down(p, off);
    if (lane == 0) out[row * 3 + g] = p + zc[g] + bl2[g];
  }
}

// ---------------------------------------------------------------------------

extern "C" void kernel_launch(void* const* d_in, const int* in_sizes, int n_in,
                              void* d_out, int out_size, void* d_ws, size_t ws_size,
                              hipStream_t stream) {
  const float* x_user  = (const float*)d_in[0];
  const float* x_movie = (const float*)d_in[1];
  const int*   e_src   = (const int*)d_in[2];
  const int*   e_dst   = (const int*)d_in[3];
  const float* W_user  = (const float*)d_in[4];
  const float* b_user  = (const float*)d_in[5];
  const float* W_movie = (const float*)d_in[6];
  const float* b_movie = (const float*)d_in[7];
  const float* Wl1_um  = (const float*)d_in[8];
  const float* bl1_um  = (const float*)d_in[9];
  const float* Wr1_um  = (const float*)d_in[10];
  const float* Wl1_mu  = (const float*)d_in[11];
  const float* bl1_mu  = (const float*)d_in[12];
  const float* Wr1_mu  = (const float*)d_in[13];
  const float* Wl2_um  = (const float*)d_in[14];
  const float* bl2_um  = (const float*)d_in[15];
  const float* Wr2_um  = (const float*)d_in[16];
  float* outp = (float*)d_out;

  // ---- workspace carve-up ----
  char* p = (char*)d_ws;
  size_t off = 0;
  auto take = [&](size_t bytes) { void* r = p + off; off += alignup(bytes); return r; };

  int* rp_m    = (int*)take(size_t(NM + 1) * 4);
  int* rp_u    = (int*)take(size_t(NU + 1) * 4);
  int* bh      = (int*)take(size_t(NBK) * 4);
  int* bbase_m = (int*)take(size_t(MBK + 1) * 4);
  int* bbase_u = (int*)take(size_t(UBK + 1) * 4);
  int* bcur_m  = (int*)take(size_t(MBK) * 4);
  int* bcur_u  = (int*)take(size_t(UBK) * 4);
  int* csr_m   = (int*)take(size_t(NE) * 4);
  int* csr_u   = (int*)take(size_t(NE) * 4);

  // overlay: staging (build phase) aliases feature buffers (feature phase)
  size_t ov_base = off;
  unsigned* stage_m = (unsigned*)take(size_t(NE) * 4);
  unsigned* stage_u = (unsigned*)take(size_t(NE) * 4);
  size_t stage_end = off;
  off = ov_base;
  unsigned short* hu = (unsigned short*)take(size_t(NU) * HD * 2);
  unsigned short* hm = (unsigned short*)take(size_t(NM) * HD * 2);
  unsigned short* u1 = (unsigned short*)take(size_t(NU) * HD * 2);
  float* m1   = (float*)take(size_t(NM) * HD * 4);
  float* aggb = (float*)take(size_t(NU) * HD * 4);
  if (off < stage_end) off = stage_end;
  float4* z    = (float4*)take(size_t(NU) * 16);
  float4* zagg = (float4*)take(size_t(NM) * 16);
  if (off > ws_size) return;

  const int TB = 256;

  // ---- CSR build ----
  hipMemsetAsync(bh, 0, size_t(NBK) * 4, stream);
  histB_kernel<<<512, 256, 0, stream>>>(e_src, e_dst, bh);
  scanB_kernel<<<1, 1024, 0, stream>>>(bh, bbase_m, bbase_u, bcur_m, bcur_u);
  passA_kernel<<<(NE + EPB - 1) / EPB, 1024, 0, stream>>>(e_src, e_dst, bcur_m, bcur_u,
                                                          stage_m, stage_u);
  passB_kernel<<<NBK, 1024, 0, stream>>>(bbase_m, bbase_u, stage_m, stage_u,
                                         csr_m, csr_u, rp_m, rp_u);

  // ---- projections ----
  proj_user_kernel<<<NU / 16, TB, 0, stream>>>(x_user, W_user, b_user, hu);
  proj_movie_kernel<<<(NM + 127) / 128, 128, 0, stream>>>(x_movie, W_movie, b_movie, hm);

  // ---- layer 1: movie side ----
  agg_mean_kernel<<<(NM + 3) / 4, TB, 0, stream>>>(hu, rp_m, csr_m, aggb, NM);
  sage64_kernel<0><<<(NM + 31) / 32, TB, 0, stream>>>(aggb, hm, Wl1_um, bl1_um, Wr1_um, m1, NM);

  // ---- layer 1: user side ----
  agg_mean_kernel<<<(NU + 3) / 4, TB, 0, stream>>>(hm, rp_u, csr_u, aggb, NU);
  sage64_kernel<1><<<(NU + 31) / 32, TB, 0, stream>>>(aggb, hu, Wl1_mu, bl1_mu, Wr1_mu, u1, NU);

  // ---- layer 2 (z-trick): project u1 -> z, aggregate z, combine ----
  zproj_kernel<<<(NU + 15) / 16, TB, 0, stream>>>(u1, Wl2_um, z);
  agg4_kernel<<<(NM + 3) / 4, TB, 0, stream>>>(z, rp_m, csr_m, zagg, NM);
  out2_kernel<<<(NM + 3) / 4, TB, 0, stream>>>(zagg, m1, Wr2_um, bl2_um, outp, NM);
}

// Round 9
// 499.663 us; speedup vs baseline: 1.1331x; 1.1331x over previous
//
#include <hip/hip_runtime.h>

// ---------------------------------------------------------------------------
// Hetero GraphSAGE (user<->movie). Bucketed CSR build, bf16 gather tables,
// register-tiled GEMMs, layer-2 project-before-aggregate (z-trick).
// ---------------------------------------------------------------------------

constexpr int NU = 100000;   // users
constexpr int NM = 50000;    // movies
constexpr int NE = 4000000;  // edges
constexpr int FU = 24;       // user feat
constexpr int FM = 404;      // movie feat
constexpr int HD = 64;       // hidden

constexpr int BSH = 8;                       // bucket = 256 node ids
constexpr int MBK = (NM + 255) >> BSH;       // 196 movie buckets
constexpr int UBK = (NU + 255) >> BSH;       // 391 user buckets
constexpr int NBK = MBK + UBK;               // 587
constexpr int EPB = 8192;                    // edges per passA block

static inline size_t alignup(size_t x) { return (x + 255) & ~size_t(255); }

__device__ __forceinline__ float bf2f(unsigned short h) {
  return __uint_as_float(((unsigned int)h) << 16);
}
__device__ __forceinline__ unsigned short f2bf(float f) {
  unsigned int u = __float_as_uint(f);
  u = (u + 0x7FFFu + ((u >> 16) & 1u)) >> 16;   // RNE
  return (unsigned short)u;
}
__device__ __forceinline__ float2 unpk(unsigned u) {
  return make_float2(__uint_as_float(u << 16), __uint_as_float(u & 0xFFFF0000u));
}

// ---------------- CSR build ----------------

__global__ __launch_bounds__(256) void histB_kernel(const int* __restrict__ src,
                                                    const int* __restrict__ dst,
                                                    int* __restrict__ bh) {
  __shared__ int h[NBK];
  for (int i = threadIdx.x; i < NBK; i += 256) h[i] = 0;
  __syncthreads();
  int idx = blockIdx.x * 256 + threadIdx.x;
  int stride = gridDim.x * 256;
  for (int i = idx; i < NE; i += stride) {
    atomicAdd(&h[dst[i] >> BSH], 1);
    atomicAdd(&h[MBK + (src[i] >> BSH)], 1);
  }
  __syncthreads();
  for (int i = threadIdx.x; i < NBK; i += 256) {
    int c = h[i];
    if (c) atomicAdd(&bh[i], c);
  }
}

__global__ __launch_bounds__(1024) void scanB_kernel(const int* __restrict__ bh,
                                                     int* __restrict__ bbase_m,
                                                     int* __restrict__ bbase_u,
                                                     int* __restrict__ bcur_m,
                                                     int* __restrict__ bcur_u) {
  __shared__ int tmp[1024];
  int t = threadIdx.x;
  int vm = (t < MBK) ? bh[t] : 0;
  tmp[t] = vm;
  __syncthreads();
  for (int off = 1; off < 1024; off <<= 1) {
    int v = (t >= off) ? tmp[t - off] : 0;
    __syncthreads();
    tmp[t] += v;
    __syncthreads();
  }
  if (t < MBK) {
    int e = tmp[t] - vm;
    bbase_m[t] = e; bcur_m[t] = e;
    if (t == MBK - 1) bbase_m[MBK] = tmp[t];
  }
  __syncthreads();
  int vu = (t < UBK) ? bh[MBK + t] : 0;
  tmp[t] = vu;
  __syncthreads();
  for (int off = 1; off < 1024; off <<= 1) {
    int v = (t >= off) ? tmp[t - off] : 0;
    __syncthreads();
    tmp[t] += v;
    __syncthreads();
  }
  if (t < UBK) {
    int e = tmp[t] - vu;
    bbase_u[t] = e; bcur_u[t] = e;
    if (t == UBK - 1) bbase_u[UBK] = tmp[t];
  }
}

__global__ __launch_bounds__(1024) void passA_kernel(
    const int* __restrict__ src, const int* __restrict__ dst,
    int* __restrict__ bcur_m, int* __restrict__ bcur_u,
    unsigned* __restrict__ stage_m, unsigned* __restrict__ stage_u) {
  __shared__ int hB[NBK];
  int t = threadIdx.x;
  for (int i = t; i < NBK; i += 1024) hB[i] = 0;
  __syncthreads();
  int e0 = blockIdx.x * EPB + t;
  int sv[8], dv[8], rm[8], ru[8];
#pragma unroll
  for (int k = 0; k < 8; ++k) {
    int e = e0 + k * 1024;
    if (e < NE) {
      int s = src[e], d = dst[e];
      sv[k] = s; dv[k] = d;
      rm[k] = atomicAdd(&hB[d >> BSH], 1);
      ru[k] = atomicAdd(&hB[MBK + (s >> BSH)], 1);
    } else {
      sv[k] = -1;
    }
  }
  __syncthreads();
  for (int i = t; i < NBK; i += 1024) {
    int c = hB[i];
    int base = 0;
    if (c) base = (i < MBK) ? atomicAdd(&bcur_m[i], c) : atomicAdd(&bcur_u[i - MBK], c);
    hB[i] = base;
  }
  __syncthreads();
#pragma unroll
  for (int k = 0; k < 8; ++k) {
    if (sv[k] >= 0) {
      int s = sv[k], d = dv[k];
      stage_m[hB[d >> BSH] + rm[k]] = ((unsigned)(d & 255) << 24) | (unsigned)s;
      stage_u[hB[MBK + (s >> BSH)] + ru[k]] = ((unsigned)(s & 255) << 24) | (unsigned)d;
    }
  }
}

__global__ __launch_bounds__(1024) void passB_kernel(
    const int* __restrict__ bbase_m, const int* __restrict__ bbase_u,
    const unsigned* __restrict__ stage_m, const unsigned* __restrict__ stage_u,
    int* __restrict__ csr_m, int* __restrict__ csr_u,
    int* __restrict__ rp_m, int* __restrict__ rp_u) {
  __shared__ int cnt[256];
  __shared__ int sc[256];
  int b = blockIdx.x;
  const unsigned* stage; int* csr; int* rp; int idbase, ntot, bb, be;
  if (b < MBK) {
    stage = stage_m; csr = csr_m; rp = rp_m;
    idbase = b << BSH; ntot = NM;
    bb = bbase_m[b]; be = bbase_m[b + 1];
  } else {
    int c = b - MBK;
    stage = stage_u; csr = csr_u; rp = rp_u;
    idbase = c << BSH; ntot = NU;
    bb = bbase_u[c]; be = bbase_u[c + 1];
  }
  int nloc = min(256, ntot - idbase);
  int t = threadIdx.x;
  if (t < 256) cnt[t] = 0;
  __syncthreads();
  for (int j = bb + t; j < be; j += 1024) atomicAdd(&cnt[stage[j] >> 24], 1);
  __syncthreads();
  int c0 = (t < 256) ? cnt[t] : 0;
  if (t < 256) sc[t] = c0;
  __syncthreads();
  for (int off = 1; off < 256; off <<= 1) {
    int v = 0;
    if (t < 256 && t >= off) v = sc[t - off];
    __syncthreads();
    if (t < 256) sc[t] += v;
    __syncthreads();
  }
  if (t < nloc) {
    int e = bb + sc[t] - c0;
    rp[idbase + t] = e;
    cnt[t] = e;                     // reuse as cursor
  }
  if (t == 0 && idbase + nloc == ntot) rp[ntot] = be;
  __syncthreads();
  for (int j = bb + t; j < be; j += 1024) {
    unsigned e = stage[j];
    int pos = atomicAdd(&cnt[e >> 24], 1);
    csr[pos] = (int)(e & 0xFFFFFFu);
  }
}

// ---------------- input projections (write bf16 tables) ----------------

__global__ void proj_user_kernel(const float* __restrict__ xu, const float* __restrict__ Wu,
                                 const float* __restrict__ bu, unsigned short* __restrict__ hu) {
  __shared__ float Wt[FU][HD + 1];
  __shared__ float Xl[16][FU];
  int t = threadIdx.x;
  int lane = t & 63, wg = t >> 6;
  int row0 = blockIdx.x * 16;
  for (int h = wg; h < HD; h += 4)
    if (lane < FU) Wt[lane][h] = Wu[h * FU + lane];
  for (int r = wg; r < 16; r += 4)
    if (lane < FU) Xl[r][lane] = xu[(row0 + r) * FU + lane];
  __syncthreads();
  float b = bu[lane];
  float acc[4] = {0.f, 0.f, 0.f, 0.f};
  for (int k = 0; k < FU; ++k) {
    float w = Wt[k][lane];
#pragma unroll
    for (int j = 0; j < 4; ++j) acc[j] += Xl[wg * 4 + j][k] * w;
  }
#pragma unroll
  for (int j = 0; j < 4; ++j)
    hu[(row0 + wg * 4 + j) * HD + lane] = f2bf(acc[j] + b);
}

// Movie projection: register-tiled GEMM, both operands read as b128.
// (Round-7 configuration: measured 92.8us, 44 VGPR, 782 blocks.)
__global__ __launch_bounds__(256, 3) void proj_movie_kernel(
    const float* __restrict__ xm, const float* __restrict__ Wm,
    const float* __restrict__ bm, unsigned short* __restrict__ hm) {
  __shared__ float Ws[64][64];   // [h][kk] swizzled
  __shared__ float Xs[64][64];   // [r][kk] swizzled
  int t = threadIdx.x;
  int row0 = blockIdx.x * 64;
  int cl = (t & 15) * 4;         // col group (output h)
  int rg = (t >> 4) * 4;         // row group
  int sw = ((cl >> 2) & 7) << 2;
  int sx = ((rg >> 2) & 3) << 2;
  float acc[4][4];
#pragma unroll
  for (int j = 0; j < 4; ++j)
#pragma unroll
    for (int c = 0; c < 4; ++c) acc[j][c] = 0.f;

  for (int k0 = 0; k0 < FM; k0 += 64) {
    int kc = min(64, FM - k0);
    __syncthreads();
    if (kc == 64) {
      for (int i = t; i < 1024; i += 256) {
        int h = i >> 4, c4 = i & 15;
        int col = c4 * 4;
        float4 wv = *(const float4*)(Wm + (size_t)h * FM + k0 + col);
        *(float4*)&Ws[h][col ^ (((h >> 2) & 7) << 2)] = wv;
        float4 xv = make_float4(0.f, 0.f, 0.f, 0.f);
        if (row0 + h < NM)
          xv = *(const float4*)(xm + (size_t)(row0 + h) * FM + k0 + col);
        *(float4*)&Xs[h][col ^ (((h >> 2) & 3) << 2)] = xv;
      }
    } else {
      for (int i = t; i < 4096; i += 256) {
        int h = i >> 6, kk = i & 63;
        float wv = (kk < kc) ? Wm[(size_t)h * FM + k0 + kk] : 0.f;
        Ws[h][kk ^ (((h >> 2) & 7) << 2)] = wv;
        float xv = (kk < kc && row0 + h < NM) ? xm[(size_t)(row0 + h) * FM + k0 + kk] : 0.f;
        Xs[h][kk ^ (((h >> 2) & 3) << 2)] = xv;
      }
    }
    __syncthreads();
#pragma unroll 2
    for (int kk = 0; kk < 64; kk += 4) {
      int kx = kk ^ sx, kw = kk ^ sw;
      float4 x0 = *(const float4*)&Xs[rg + 0][kx];
      float4 x1 = *(const float4*)&Xs[rg + 1][kx];
      float4 x2 = *(const float4*)&Xs[rg + 2][kx];
      float4 x3 = *(const float4*)&Xs[rg + 3][kx];
      float4 w0 = *(const float4*)&Ws[cl + 0][kw];
      float4 w1 = *(const float4*)&Ws[cl + 1][kw];
      float4 w2 = *(const float4*)&Ws[cl + 2][kw];
      float4 w3 = *(const float4*)&Ws[cl + 3][kw];
#define MAC(J, XV)                                                        \
      acc[J][0] += XV.x * w0.x + XV.y * w0.y + XV.z * w0.z + XV.w * w0.w; \
      acc[J][1] += XV.x * w1.x + XV.y * w1.y + XV.z * w1.z + XV.w * w1.w; \
      acc[J][2] += XV.x * w2.x + XV.y * w2.y + XV.z * w2.z + XV.w * w2.w; \
      acc[J][3] += XV.x * w3.x + XV.y * w3.y + XV.z * w3.z + XV.w * w3.w;
      MAC(0, x0) MAC(1, x1) MAC(2, x2) MAC(3, x3)
#undef MAC
    }
  }
  float4 bv = *(const float4*)(bm + cl);
#pragma unroll
  for (int j = 0; j < 4; ++j) {
    int row = row0 + rg + j;
    if (row < NM) {
      ushort4 o;
      o.x = f2bf(acc[j][0] + bv.x);
      o.y = f2bf(acc[j][1] + bv.y);
      o.z = f2bf(acc[j][2] + bv.z);
      o.w = f2bf(acc[j][3] + bv.w);
      *(ushort4*)(hm + (size_t)row * HD + cl) = o;
    }
  }
}

// ---------------- mean aggregation: 4 neighbors/wave, 16-deep unroll ------

__global__ __launch_bounds__(256) void agg_mean_kernel(
    const unsigned short* __restrict__ table, const int* __restrict__ rp,
    const int* __restrict__ csr, float* __restrict__ out, int n) {
  int wid = threadIdx.x >> 6;
  int lane = threadIdx.x & 63;
  int row = blockIdx.x * 4 + wid;
  if (row >= n) return;
  int beg = rp[row], end = rp[row + 1];
  int g = lane >> 4;        // neighbor slot 0..3
  int fq = lane & 15;       // feature quad
  float a0 = 0.f, a1 = 0.f, a2 = 0.f, a3 = 0.f;
  int i = beg;
  for (; i + 16 <= end; i += 16) {
    int n0 = csr[i + g];
    int n1 = csr[i + 4 + g];
    int n2 = csr[i + 8 + g];
    int n3 = csr[i + 12 + g];
    uint2 v0 = *(const uint2*)(table + (size_t)n0 * HD + fq * 4);
    uint2 v1 = *(const uint2*)(table + (size_t)n1 * HD + fq * 4);
    uint2 v2 = *(const uint2*)(table + (size_t)n2 * HD + fq * 4);
    uint2 v3 = *(const uint2*)(table + (size_t)n3 * HD + fq * 4);
    float2 p0 = unpk(v0.x), p1 = unpk(v0.y);
    float2 q0 = unpk(v1.x), q1 = unpk(v1.y);
    float2 r0 = unpk(v2.x), r1 = unpk(v2.y);
    float2 s0 = unpk(v3.x), s1 = unpk(v3.y);
    a0 += (p0.x + q0.x) + (r0.x + s0.x);
    a1 += (p0.y + q0.y) + (r0.y + s0.y);
    a2 += (p1.x + q1.x) + (r1.x + s1.x);
    a3 += (p1.y + q1.y) + (r1.y + s1.y);
  }
  for (; i + 8 <= end; i += 8) {
    int n0 = csr[i + g];
    int n1 = csr[i + 4 + g];
    uint2 v0 = *(const uint2*)(table + (size_t)n0 * HD + fq * 4);
    uint2 v1 = *(const uint2*)(table + (size_t)n1 * HD + fq * 4);
    float2 p0 = unpk(v0.x), p1 = unpk(v0.y);
    float2 q0 = unpk(v1.x), q1 = unpk(v1.y);
    a0 += p0.x + q0.x; a1 += p0.y + q0.y;
    a2 += p1.x + q1.x; a3 += p1.y + q1.y;
  }
  for (; i < end; i += 4) {
    int idx = i + g;
    if (idx < end) {
      int nb = csr[idx];
      uint2 v = *(const uint2*)(table + (size_t)nb * HD + fq * 4);
      float2 p0 = unpk(v.x), p1 = unpk(v.y);
      a0 += p0.x; a1 += p0.y; a2 += p1.x; a3 += p1.y;
    }
  }
  a0 += __shfl_xor(a0, 16); a0 += __shfl_xor(a0, 32);
  a1 += __shfl_xor(a1, 16); a1 += __shfl_xor(a1, 32);
  a2 += __shfl_xor(a2, 16); a2 += __shfl_xor(a2, 32);
  a3 += __shfl_xor(a3, 16); a3 += __shfl_xor(a3, 32);
  float inv = 1.0f / fmaxf((float)(end - beg), 1.0f);
  if (lane < 16) {
    float4 o = make_float4(a0 * inv, a1 * inv, a2 * inv, a3 * inv);
    *(float4*)(out + (size_t)row * HD + fq * 4) = o;
  }
}

// ---------------- SAGE linear 64->64 + relu (register-tiled) ----------------

template <int OUTBF>
__global__ __launch_bounds__(256, 3) void sage64_kernel(
    const float* __restrict__ agg, const unsigned short* __restrict__ xd,
    const float* __restrict__ Wl, const float* __restrict__ bl,
    const float* __restrict__ Wr, void* __restrict__ outp, int n) {
  __shared__ float Ws[128][65];     // [k][h], padded (scalar reads only)
  __shared__ float Xs[32][128];     // [row][k] : k<64 agg, k>=64 x
  int t = threadIdx.x;
  int lane = t & 63, wid = t >> 6;
  int row0 = blockIdx.x * 32;
  for (int i = t; i < 4096; i += 256) {
    int h = i >> 6, k = i & 63;
    Ws[k][h] = Wl[i];
  }
  for (int i = t; i < 4096; i += 256) {
    int h = i >> 6, k = i & 63;
    Ws[64 + k][h] = Wr[i];
  }
  for (int i = t; i < 512; i += 256) {
    int r = i >> 4, c4 = i & 15;
    if (row0 + r < n) {
      float4 v = ((const float4*)(agg + (size_t)(row0 + r) * HD))[c4];
      *(float4*)&Xs[r][c4 * 4] = v;
    }
  }
  for (int i = t; i < 512; i += 256) {
    int r = i >> 4, c4 = i & 15;
    if (row0 + r < n) {
      uint2 v = ((const uint2*)(xd + (size_t)(row0 + r) * HD))[c4];
      float2 p0 = unpk(v.x), p1 = unpk(v.y);
      *(float4*)&Xs[r][64 + c4 * 4] = make_float4(p0.x, p0.y, p1.x, p1.y);
    }
  }
  __syncthreads();
  float acc[8] = {0.f, 0.f, 0.f, 0.f, 0.f, 0.f, 0.f, 0.f};
  int rbase = wid * 8;
#pragma unroll 4
  for (int k = 0; k < 128; ++k) {
    float wv = Ws[k][lane];
#pragma unroll
    for (int j = 0; j < 8; ++j) acc[j] += Xs[rbase + j][k] * wv;
  }
  float b = bl[lane];
#pragma unroll
  for (int j = 0; j < 8; ++j) {
    int row = row0 + rbase + j;
    if (row < n) {
      float v = fmaxf(acc[j] + b, 0.f);
      if (OUTBF) ((unsigned short*)outp)[(size_t)row * HD + lane] = f2bf(v);
      else       ((float*)outp)[(size_t)row * HD + lane] = v;
    }
  }
}

// ---------------- layer 2 (z-trick): project u1 -> z[NU][4] ----------------

__global__ __launch_bounds__(256) void zproj_kernel(
    const unsigned short* __restrict__ u1, const float* __restrict__ Wl2,
    float4* __restrict__ z) {
  __shared__ float W[3][64];
  int t = threadIdx.x;
  if (t < 192) W[t / 64][t & 63] = Wl2[t];
  __syncthreads();
  int wid = t >> 6, lane = t & 63;
  int g = lane >> 4, fq = lane & 15;
  int row = blockIdx.x * 16 + wid * 4 + g;
  if (row >= NU) return;
  uint2 v = *(const uint2*)(u1 + (size_t)row * HD + fq * 4);
  float2 p0 = unpk(v.x), p1 = unpk(v.y);
  int f = fq * 4;
  float z0 = p0.x * W[0][f] + p0.y * W[0][f + 1] + p1.x * W[0][f + 2] + p1.y * W[0][f + 3];
  float z1 = p0.x * W[1][f] + p0.y * W[1][f + 1] + p1.x * W[1][f + 2] + p1.y * W[1][f + 3];
  float z2 = p0.x * W[2][f] + p0.y * W[2][f + 1] + p1.x * W[2][f + 2] + p1.y * W[2][f + 3];
#pragma unroll
  for (int off = 1; off < 16; off <<= 1) {
    z0 += __shfl_xor(z0, off);
    z1 += __shfl_xor(z1, off);
    z2 += __shfl_xor(z2, off);
  }
  if (fq == 0) z[row] = make_float4(z0, z1, z2, 0.f);
}

// agg4: mean of z over movie neighborhoods. 16B/edge gather (L2-resident).
__global__ __launch_bounds__(256) void agg4_kernel(
    const float4* __restrict__ z, const int* __restrict__ rp,
    const int* __restrict__ csr, float4* __restrict__ zagg, int n) {
  int wid = threadIdx.x >> 6, lane = threadIdx.x & 63;
  int row = blockIdx.x * 4 + wid;
  if (row >= n) return;
  int beg = rp[row], end = rp[row + 1];
  float s0 = 0.f, s1 = 0.f, s2 = 0.f;
  for (int i = beg + lane; i < end; i += 64) {
    float4 v = z[csr[i]];
    s0 += v.x; s1 += v.y; s2 += v.z;
  }
#pragma unroll
  for (int off = 1; off < 64; off <<= 1) {
    s0 += __shfl_xor(s0, off);
    s1 += __shfl_xor(s1, off);
    s2 += __shfl_xor(s2, off);
  }
  if (lane == 0) {
    float inv = 1.0f / fmaxf((float)(end - beg), 1.0f);
    zagg[row] = make_float4(s0 * inv, s1 * inv, s2 * inv, 0.f);
  }
}

// out2: out[m][g] = zagg[m][g] + bl2[g] + m1[m] . Wr2[g]
__global__ void out2_kernel(const float4* __restrict__ zagg, const float* __restrict__ m1,
                            const float* __restrict__ Wr2, const float* __restrict__ bl2,
                            float* __restrict__ out, int n) {
  int wid = threadIdx.x >> 6, lane = threadIdx.x & 63;
  int row = blockIdx.x * 4 + wid;
  if (row >= n) return;
  float mm = m1[(size_t)row * HD + lane];
  float4 za = zagg[row];
  float zc[3] = {za.x, za.y, za.z};
#pragma unroll
  for (int g = 0; g < 3; ++g) {
    float p = mm * Wr2[g * HD + lane];
#pragma unroll
    for (int off = 32; off > 0; off >>= 1) p += __shfl_down(p, off);
    if (lane == 0) out[row * 3 + g] = p + zc[g] + bl2[g];
  }
}

// ---------------------------------------------------------------------------

extern "C" void kernel_launch(void* const* d_in, const int* in_sizes, int n_in,
                              void* d_out, int out_size, void* d_ws, size_t ws_size,
                              hipStream_t stream) {
  const float* x_user  = (const float*)d_in[0];
  const float* x_movie = (const float*)d_in[1];
  const int*   e_src   = (const int*)d_in[2];
  const int*   e_dst   = (const int*)d_in[3];
  const float* W_user  = (const float*)d_in[4];
  const float* b_user  = (const float*)d_in[5];
  const float* W_movie = (const float*)d_in[6];
  const float* b_movie = (const float*)d_in[7];
  const float* Wl1_um  = (const float*)d_in[8];
  const float* bl1_um  = (const float*)d_in[9];
  const float* Wr1_um  = (const float*)d_in[10];
  const float* Wl1_mu  = (const float*)d_in[11];
  const float* bl1_mu  = (const float*)d_in[12];
  const float* Wr1_mu  = (const float*)d_in[13];
  const float* Wl2_um  = (const float*)d_in[14];
  const float* bl2_um  = (const float*)d_in[15];
  const float* Wr2_um  = (const float*)d_in[16];
  float* outp = (float*)d_out;

  // ---- workspace carve-up ----
  char* p = (char*)d_ws;
  size_t off = 0;
  auto take = [&](size_t bytes) { void* r = p + off; off += alignup(bytes); return r; };

  int* rp_m    = (int*)take(size_t(NM + 1) * 4);
  int* rp_u    = (int*)take(size_t(NU + 1) * 4);
  int* bh      = (int*)take(size_t(NBK) * 4);
  int* bbase_m = (int*)take(size_t(MBK + 1) * 4);
  int* bbase_u = (int*)take(size_t(UBK + 1) * 4);
  int* bcur_m  = (int*)take(size_t(MBK) * 4);
  int* bcur_u  = (int*)take(size_t(UBK) * 4);
  int* csr_m   = (int*)take(size_t(NE) * 4);
  int* csr_u   = (int*)take(size_t(NE) * 4);

  // overlay: staging (build phase) aliases feature buffers (feature phase)
  size_t ov_base = off;
  unsigned* stage_m = (unsigned*)take(size_t(NE) * 4);
  unsigned* stage_u = (unsigned*)take(size_t(NE) * 4);
  size_t stage_end = off;
  off = ov_base;
  unsigned short* hu = (unsigned short*)take(size_t(NU) * HD * 2);
  unsigned short* hm = (unsigned short*)take(size_t(NM) * HD * 2);
  unsigned short* u1 = (unsigned short*)take(size_t(NU) * HD * 2);
  float* m1   = (float*)take(size_t(NM) * HD * 4);
  float* aggb = (float*)take(size_t(NU) * HD * 4);
  if (off < stage_end) off = stage_end;
  float4* z    = (float4*)take(size_t(NU) * 16);
  float4* zagg = (float4*)take(size_t(NM) * 16);
  if (off > ws_size) return;

  const int TB = 256;

  // ---- CSR build ----
  hipMemsetAsync(bh, 0, size_t(NBK) * 4, stream);
  histB_kernel<<<512, 256, 0, stream>>>(e_src, e_dst, bh);
  scanB_kernel<<<1, 1024, 0, stream>>>(bh, bbase_m, bbase_u, bcur_m, bcur_u);
  passA_kernel<<<(NE + EPB - 1) / EPB, 1024, 0, stream>>>(e_src, e_dst, bcur_m, bcur_u,
                                                          stage_m, stage_u);
  passB_kernel<<<NBK, 1024, 0, stream>>>(bbase_m, bbase_u, stage_m, stage_u,
                                         csr_m, csr_u, rp_m, rp_u);

  // ---- projections ----
  proj_user_kernel<<<NU / 16, TB, 0, stream>>>(x_user, W_user, b_user, hu);
  proj_movie_kernel<<<(NM + 63) / 64, TB, 0, stream>>>(x_movie, W_movie, b_movie, hm);

  // ---- layer 1: movie side ----
  agg_mean_kernel<<<(NM + 3) / 4, TB, 0, stream>>>(hu, rp_m, csr_m, aggb, NM);
  sage64_kernel<0><<<(NM + 31) / 32, TB, 0, stream>>>(aggb, hm, Wl1_um, bl1_um, Wr1_um, m1, NM);

  // ---- layer 1: user side ----
  agg_mean_kernel<<<(NU + 3) / 4, TB, 0, stream>>>(hm, rp_u, csr_u, aggb, NU);
  sage64_kernel<1><<<(NU + 31) / 32, TB, 0, stream>>>(aggb, hu, Wl1_mu, bl1_mu, Wr1_mu, u1, NU);

  // ---- layer 2 (z-trick): project u1 -> z, aggregate z, combine ----
  zproj_kernel<<<(NU + 15) / 16, TB, 0, stream>>>(u1, Wl2_um, z);
  agg4_kernel<<<(NM + 3) / 4, TB, 0, stream>>>(z, rp_m, csr_m, zagg, NM);
  out2_kernel<<<(NM + 3) / 4, TB, 0, stream>>>(zagg, m1, Wr2_um, bl2_um, outp, NM);
}

// Round 10
// 451.722 us; speedup vs baseline: 1.2534x; 1.1061x over previous
//
#include <hip/hip_runtime.h>

// ---------------------------------------------------------------------------
// Hetero GraphSAGE (user<->movie). Bucketed CSR build, bf16 gather tables,
// MFMA movie projection, register-tiled SAGE linear, layer-2 z-trick.
// ---------------------------------------------------------------------------

constexpr int NU = 100000;   // users
constexpr int NM = 50000;    // movies
constexpr int NE = 4000000;  // edges
constexpr int FU = 24;       // user feat
constexpr int FM = 404;      // movie feat
constexpr int HD = 64;       // hidden

constexpr int BSH = 8;                       // bucket = 256 node ids
constexpr int MBK = (NM + 255) >> BSH;       // 196 movie buckets
constexpr int UBK = (NU + 255) >> BSH;       // 391 user buckets
constexpr int NBK = MBK + UBK;               // 587
constexpr int EPB = 8192;                    // edges per passA block

static inline size_t alignup(size_t x) { return (x + 255) & ~size_t(255); }

__device__ __forceinline__ float bf2f(unsigned short h) {
  return __uint_as_float(((unsigned int)h) << 16);
}
__device__ __forceinline__ unsigned short f2bf(float f) {
  unsigned int u = __float_as_uint(f);
  u = (u + 0x7FFFu + ((u >> 16) & 1u)) >> 16;   // RNE
  return (unsigned short)u;
}
__device__ __forceinline__ float2 unpk(unsigned u) {
  return make_float2(__uint_as_float(u << 16), __uint_as_float(u & 0xFFFF0000u));
}

using bf16x8 = __attribute__((ext_vector_type(8))) short;   // 8 bf16 = 4 VGPRs
using f32x4  = __attribute__((ext_vector_type(4))) float;   // MFMA C/D frag

// ---------------- CSR build ----------------

__global__ __launch_bounds__(256) void histB_kernel(const int* __restrict__ src,
                                                    const int* __restrict__ dst,
                                                    int* __restrict__ bh) {
  __shared__ int h[NBK];
  for (int i = threadIdx.x; i < NBK; i += 256) h[i] = 0;
  __syncthreads();
  int idx = blockIdx.x * 256 + threadIdx.x;
  int stride = gridDim.x * 256;
  for (int i = idx; i < NE; i += stride) {
    atomicAdd(&h[dst[i] >> BSH], 1);
    atomicAdd(&h[MBK + (src[i] >> BSH)], 1);
  }
  __syncthreads();
  for (int i = threadIdx.x; i < NBK; i += 256) {
    int c = h[i];
    if (c) atomicAdd(&bh[i], c);
  }
}

__global__ __launch_bounds__(1024) void scanB_kernel(const int* __restrict__ bh,
                                                     int* __restrict__ bbase_m,
                                                     int* __restrict__ bbase_u,
                                                     int* __restrict__ bcur_m,
                                                     int* __restrict__ bcur_u) {
  __shared__ int tmp[1024];
  int t = threadIdx.x;
  int vm = (t < MBK) ? bh[t] : 0;
  tmp[t] = vm;
  __syncthreads();
  for (int off = 1; off < 1024; off <<= 1) {
    int v = (t >= off) ? tmp[t - off] : 0;
    __syncthreads();
    tmp[t] += v;
    __syncthreads();
  }
  if (t < MBK) {
    int e = tmp[t] - vm;
    bbase_m[t] = e; bcur_m[t] = e;
    if (t == MBK - 1) bbase_m[MBK] = tmp[t];
  }
  __syncthreads();
  int vu = (t < UBK) ? bh[MBK + t] : 0;
  tmp[t] = vu;
  __syncthreads();
  for (int off = 1; off < 1024; off <<= 1) {
    int v = (t >= off) ? tmp[t - off] : 0;
    __syncthreads();
    tmp[t] += v;
    __syncthreads();
  }
  if (t < UBK) {
    int e = tmp[t] - vu;
    bbase_u[t] = e; bcur_u[t] = e;
    if (t == UBK - 1) bbase_u[UBK] = tmp[t];
  }
}

__global__ __launch_bounds__(1024) void passA_kernel(
    const int* __restrict__ src, const int* __restrict__ dst,
    int* __restrict__ bcur_m, int* __restrict__ bcur_u,
    unsigned* __restrict__ stage_m, unsigned* __restrict__ stage_u) {
  __shared__ int hB[NBK];
  int t = threadIdx.x;
  for (int i = t; i < NBK; i += 1024) hB[i] = 0;
  __syncthreads();
  int e0 = blockIdx.x * EPB + t;
  int sv[8], dv[8], rm[8], ru[8];
#pragma unroll
  for (int k = 0; k < 8; ++k) {
    int e = e0 + k * 1024;
    if (e < NE) {
      int s = src[e], d = dst[e];
      sv[k] = s; dv[k] = d;
      rm[k] = atomicAdd(&hB[d >> BSH], 1);
      ru[k] = atomicAdd(&hB[MBK + (s >> BSH)], 1);
    } else {
      sv[k] = -1;
    }
  }
  __syncthreads();
  for (int i = t; i < NBK; i += 1024) {
    int c = hB[i];
    int base = 0;
    if (c) base = (i < MBK) ? atomicAdd(&bcur_m[i], c) : atomicAdd(&bcur_u[i - MBK], c);
    hB[i] = base;
  }
  __syncthreads();
#pragma unroll
  for (int k = 0; k < 8; ++k) {
    if (sv[k] >= 0) {
      int s = sv[k], d = dv[k];
      stage_m[hB[d >> BSH] + rm[k]] = ((unsigned)(d & 255) << 24) | (unsigned)s;
      stage_u[hB[MBK + (s >> BSH)] + ru[k]] = ((unsigned)(s & 255) << 24) | (unsigned)d;
    }
  }
}

__global__ __launch_bounds__(1024) void passB_kernel(
    const int* __restrict__ bbase_m, const int* __restrict__ bbase_u,
    const unsigned* __restrict__ stage_m, const unsigned* __restrict__ stage_u,
    int* __restrict__ csr_m, int* __restrict__ csr_u,
    int* __restrict__ rp_m, int* __restrict__ rp_u) {
  __shared__ int cnt[256];
  __shared__ int sc[256];
  int b = blockIdx.x;
  const unsigned* stage; int* csr; int* rp; int idbase, ntot, bb, be;
  if (b < MBK) {
    stage = stage_m; csr = csr_m; rp = rp_m;
    idbase = b << BSH; ntot = NM;
    bb = bbase_m[b]; be = bbase_m[b + 1];
  } else {
    int c = b - MBK;
    stage = stage_u; csr = csr_u; rp = rp_u;
    idbase = c << BSH; ntot = NU;
    bb = bbase_u[c]; be = bbase_u[c + 1];
  }
  int nloc = min(256, ntot - idbase);
  int t = threadIdx.x;
  if (t < 256) cnt[t] = 0;
  __syncthreads();
  for (int j = bb + t; j < be; j += 1024) atomicAdd(&cnt[stage[j] >> 24], 1);
  __syncthreads();
  int c0 = (t < 256) ? cnt[t] : 0;
  if (t < 256) sc[t] = c0;
  __syncthreads();
  for (int off = 1; off < 256; off <<= 1) {
    int v = 0;
    if (t < 256 && t >= off) v = sc[t - off];
    __syncthreads();
    if (t < 256) sc[t] += v;
    __syncthreads();
  }
  if (t < nloc) {
    int e = bb + sc[t] - c0;
    rp[idbase + t] = e;
    cnt[t] = e;                     // reuse as cursor
  }
  if (t == 0 && idbase + nloc == ntot) rp[ntot] = be;
  __syncthreads();
  for (int j = bb + t; j < be; j += 1024) {
    unsigned e = stage[j];
    int pos = atomicAdd(&cnt[e >> 24], 1);
    csr[pos] = (int)(e & 0xFFFFFFu);
  }
}

// ---------------- input projections (write bf16 tables) ----------------

__global__ void proj_user_kernel(const float* __restrict__ xu, const float* __restrict__ Wu,
                                 const float* __restrict__ bu, unsigned short* __restrict__ hu) {
  __shared__ float Wt[FU][HD + 1];
  __shared__ float Xl[16][FU];
  int t = threadIdx.x;
  int lane = t & 63, wg = t >> 6;
  int row0 = blockIdx.x * 16;
  for (int h = wg; h < HD; h += 4)
    if (lane < FU) Wt[lane][h] = Wu[h * FU + lane];
  for (int r = wg; r < 16; r += 4)
    if (lane < FU) Xl[r][lane] = xu[(row0 + r) * FU + lane];
  __syncthreads();
  float b = bu[lane];
  float acc[4] = {0.f, 0.f, 0.f, 0.f};
  for (int k = 0; k < FU; ++k) {
    float w = Wt[k][lane];
#pragma unroll
    for (int j = 0; j < 4; ++j) acc[j] += Xl[wg * 4 + j][k] * w;
  }
#pragma unroll
  for (int j = 0; j < 4; ++j)
    hu[(row0 + wg * 4 + j) * HD + lane] = f2bf(acc[j] + b);
}

// W_movie fp32 -> bf16 (once per launch)
__global__ void convW_kernel(const float* __restrict__ W, unsigned short* __restrict__ Wb,
                             int n) {
  int i = blockIdx.x * 256 + threadIdx.x;
  if (i < n) Wb[i] = f2bf(W[i]);
}

// Movie projection via MFMA: block = 64 rows x 64 cols, 4 waves, each wave
// 16 rows x 64 cols (4 C-frags). K chunked by 64 (zero-filled tail).
// LDS tiles stride 72 shorts (144B, odd multiple of 16B): b128 frag reads
// tile the 32 banks evenly (8 lanes/4-bank span = b128 BW floor).
__global__ __launch_bounds__(256) void proj_movie_kernel(
    const float* __restrict__ xm, const unsigned short* __restrict__ Wb,
    const float* __restrict__ bm, unsigned short* __restrict__ hm) {
  __shared__ unsigned short Xs[64][72];
  __shared__ unsigned short Ws[64][72];
  int t = threadIdx.x;
  int lane = t & 63, wid = t >> 6;
  int row0 = blockIdx.x * 64;
  int r0 = wid * 16;
  f32x4 acc[4];
#pragma unroll
  for (int nt = 0; nt < 4; ++nt) acc[nt] = (f32x4){0.f, 0.f, 0.f, 0.f};

  for (int k0 = 0; k0 < 448; k0 += 64) {
    int kc = min(64, FM - k0);      // 64, tail 20 (= exactly 5 float4 groups)
    __syncthreads();
    // stage X: fp32 -> bf16, 64 rows x 16 float4 groups
    for (int i = t; i < 1024; i += 256) {
      int r = i >> 4, c4 = i & 15;
      float4 v = make_float4(0.f, 0.f, 0.f, 0.f);
      if (c4 * 4 < kc && row0 + r < NM)
        v = *(const float4*)(xm + (size_t)(row0 + r) * FM + k0 + c4 * 4);
      ushort4 o;
      o.x = f2bf(v.x); o.y = f2bf(v.y); o.z = f2bf(v.z); o.w = f2bf(v.w);
      *(ushort4*)&Xs[r][c4 * 4] = o;
    }
    // stage W (already bf16): 64 cols x 16 uint2 groups (4 bf16 each)
    for (int i = t; i < 1024; i += 256) {
      int h = i >> 4, c4 = i & 15;
      uint2 v = make_uint2(0u, 0u);
      if (c4 * 4 < kc)
        v = *(const uint2*)(Wb + (size_t)h * FM + k0 + c4 * 4);
      *(uint2*)&Ws[h][c4 * 4] = v;
    }
    __syncthreads();
#pragma unroll
    for (int kk = 0; kk < 64; kk += 32) {
      // A frag: row = r0 + (lane&15), k = kk + (lane>>4)*8 .. +8
      bf16x8 a = *(const bf16x8*)&Xs[r0 + (lane & 15)][kk + (lane >> 4) * 8];
#pragma unroll
      for (int nt = 0; nt < 4; ++nt) {
        bf16x8 b = *(const bf16x8*)&Ws[nt * 16 + (lane & 15)][kk + (lane >> 4) * 8];
        acc[nt] = __builtin_amdgcn_mfma_f32_16x16x32_bf16(a, b, acc[nt], 0, 0, 0);
      }
    }
  }
  // epilogue: C/D layout col = lane&15, row = (lane>>4)*4 + j  [m89]
  int col = lane & 15;
  int rbase = r0 + (lane >> 4) * 4;
#pragma unroll
  for (int nt = 0; nt < 4; ++nt) {
    float b = bm[nt * 16 + col];
#pragma unroll
    for (int j = 0; j < 4; ++j) {
      int row = row0 + rbase + j;
      if (row < NM)
        hm[(size_t)row * HD + nt * 16 + col] = f2bf(acc[nt][j] + b);
    }
  }
}

// ---------------- mean aggregation: 4 neighbors/wave, 16-deep unroll ------

__global__ __launch_bounds__(256) void agg_mean_kernel(
    const unsigned short* __restrict__ table, const int* __restrict__ rp,
    const int* __restrict__ csr, float* __restrict__ out, int n) {
  int wid = threadIdx.x >> 6;
  int lane = threadIdx.x & 63;
  int row = blockIdx.x * 4 + wid;
  if (row >= n) return;
  int beg = rp[row], end = rp[row + 1];
  int g = lane >> 4;        // neighbor slot 0..3
  int fq = lane & 15;       // feature quad
  float a0 = 0.f, a1 = 0.f, a2 = 0.f, a3 = 0.f;
  int i = beg;
  for (; i + 16 <= end; i += 16) {
    int n0 = csr[i + g];
    int n1 = csr[i + 4 + g];
    int n2 = csr[i + 8 + g];
    int n3 = csr[i + 12 + g];
    uint2 v0 = *(const uint2*)(table + (size_t)n0 * HD + fq * 4);
    uint2 v1 = *(const uint2*)(table + (size_t)n1 * HD + fq * 4);
    uint2 v2 = *(const uint2*)(table + (size_t)n2 * HD + fq * 4);
    uint2 v3 = *(const uint2*)(table + (size_t)n3 * HD + fq * 4);
    float2 p0 = unpk(v0.x), p1 = unpk(v0.y);
    float2 q0 = unpk(v1.x), q1 = unpk(v1.y);
    float2 r0 = unpk(v2.x), r1 = unpk(v2.y);
    float2 s0 = unpk(v3.x), s1 = unpk(v3.y);
    a0 += (p0.x + q0.x) + (r0.x + s0.x);
    a1 += (p0.y + q0.y) + (r0.y + s0.y);
    a2 += (p1.x + q1.x) + (r1.x + s1.x);
    a3 += (p1.y + q1.y) + (r1.y + s1.y);
  }
  for (; i + 8 <= end; i += 8) {
    int n0 = csr[i + g];
    int n1 = csr[i + 4 + g];
    uint2 v0 = *(const uint2*)(table + (size_t)n0 * HD + fq * 4);
    uint2 v1 = *(const uint2*)(table + (size_t)n1 * HD + fq * 4);
    float2 p0 = unpk(v0.x), p1 = unpk(v0.y);
    float2 q0 = unpk(v1.x), q1 = unpk(v1.y);
    a0 += p0.x + q0.x; a1 += p0.y + q0.y;
    a2 += p1.x + q1.x; a3 += p1.y + q1.y;
  }
  for (; i < end; i += 4) {
    int idx = i + g;
    if (idx < end) {
      int nb = csr[idx];
      uint2 v = *(const uint2*)(table + (size_t)nb * HD + fq * 4);
      float2 p0 = unpk(v.x), p1 = unpk(v.y);
      a0 += p0.x; a1 += p0.y; a2 += p1.x; a3 += p1.y;
    }
  }
  a0 += __shfl_xor(a0, 16); a0 += __shfl_xor(a0, 32);
  a1 += __shfl_xor(a1, 16); a1 += __shfl_xor(a1, 32);
  a2 += __shfl_xor(a2, 16); a2 += __shfl_xor(a2, 32);
  a3 += __shfl_xor(a3, 16); a3 += __shfl_xor(a3, 32);
  float inv = 1.0f / fmaxf((float)(end - beg), 1.0f);
  if (lane < 16) {
    float4 o = make_float4(a0 * inv, a1 * inv, a2 * inv, a3 * inv);
    *(float4*)(out + (size_t)row * HD + fq * 4) = o;
  }
}

// ---------------- SAGE linear 64->64 + relu (register-tiled) ----------------

template <int OUTBF>
__global__ __launch_bounds__(256, 3) void sage64_kernel(
    const float* __restrict__ agg, const unsigned short* __restrict__ xd,
    const float* __restrict__ Wl, const float* __restrict__ bl,
    const float* __restrict__ Wr, void* __restrict__ outp, int n) {
  __shared__ float Ws[128][65];     // [k][h], padded (scalar reads only)
  __shared__ float Xs[32][128];     // [row][k] : k<64 agg, k>=64 x
  int t = threadIdx.x;
  int lane = t & 63, wid = t >> 6;
  int row0 = blockIdx.x * 32;
  for (int i = t; i < 4096; i += 256) {
    int h = i >> 6, k = i & 63;
    Ws[k][h] = Wl[i];
  }
  for (int i = t; i < 4096; i += 256) {
    int h = i >> 6, k = i & 63;
    Ws[64 + k][h] = Wr[i];
  }
  for (int i = t; i < 512; i += 256) {
    int r = i >> 4, c4 = i & 15;
    if (row0 + r < n) {
      float4 v = ((const float4*)(agg + (size_t)(row0 + r) * HD))[c4];
      *(float4*)&Xs[r][c4 * 4] = v;
    }
  }
  for (int i = t; i < 512; i += 256) {
    int r = i >> 4, c4 = i & 15;
    if (row0 + r < n) {
      uint2 v = ((const uint2*)(xd + (size_t)(row0 + r) * HD))[c4];
      float2 p0 = unpk(v.x), p1 = unpk(v.y);
      *(float4*)&Xs[r][64 + c4 * 4] = make_float4(p0.x, p0.y, p1.x, p1.y);
    }
  }
  __syncthreads();
  float acc[8] = {0.f, 0.f, 0.f, 0.f, 0.f, 0.f, 0.f, 0.f};
  int rbase = wid * 8;
#pragma unroll 4
  for (int k = 0; k < 128; ++k) {
    float wv = Ws[k][lane];
#pragma unroll
    for (int j = 0; j < 8; ++j) acc[j] += Xs[rbase + j][k] * wv;
  }
  float b = bl[lane];
#pragma unroll
  for (int j = 0; j < 8; ++j) {
    int row = row0 + rbase + j;
    if (row < n) {
      float v = fmaxf(acc[j] + b, 0.f);
      if (OUTBF) ((unsigned short*)outp)[(size_t)row * HD + lane] = f2bf(v);
      else       ((float*)outp)[(size_t)row * HD + lane] = v;
    }
  }
}

// ---------------- layer 2 (z-trick): project u1 -> z[NU][4] ----------------

__global__ __launch_bounds__(256) void zproj_kernel(
    const unsigned short* __restrict__ u1, const float* __restrict__ Wl2,
    float4* __restrict__ z) {
  __shared__ float W[3][64];
  int t = threadIdx.x;
  if (t < 192) W[t / 64][t & 63] = Wl2[t];
  __syncthreads();
  int wid = t >> 6, lane = t & 63;
  int g = lane >> 4, fq = lane & 15;
  int row = blockIdx.x * 16 + wid * 4 + g;
  if (row >= NU) return;
  uint2 v = *(const uint2*)(u1 + (size_t)row * HD + fq * 4);
  float2 p0 = unpk(v.x), p1 = unpk(v.y);
  int f = fq * 4;
  float z0 = p0.x * W[0][f] + p0.y * W[0][f + 1] + p1.x * W[0][f + 2] + p1.y * W[0][f + 3];
  float z1 = p0.x * W[1][f] + p0.y * W[1][f + 1] + p1.x * W[1][f + 2] + p1.y * W[1][f + 3];
  float z2 = p0.x * W[2][f] + p0.y * W[2][f + 1] + p1.x * W[2][f + 2] + p1.y * W[2][f + 3];
#pragma unroll
  for (int off = 1; off < 16; off <<= 1) {
    z0 += __shfl_xor(z0, off);
    z1 += __shfl_xor(z1, off);
    z2 += __shfl_xor(z2, off);
  }
  if (fq == 0) z[row] = make_float4(z0, z1, z2, 0.f);
}

// agg4: mean of z over movie neighborhoods. 16B/edge gather (L2-resident).
__global__ __launch_bounds__(256) void agg4_kernel(
    const float4* __restrict__ z, const int* __restrict__ rp,
    const int* __restrict__ csr, float4* __restrict__ zagg, int n) {
  int wid = threadIdx.x >> 6, lane = threadIdx.x & 63;
  int row = blockIdx.x * 4 + wid;
  if (row >= n) return;
  int beg = rp[row], end = rp[row + 1];
  float s0 = 0.f, s1 = 0.f, s2 = 0.f;
  for (int i = beg + lane; i < end; i += 64) {
    float4 v = z[csr[i]];
    s0 += v.x; s1 += v.y; s2 += v.z;
  }
#pragma unroll
  for (int off = 1; off < 64; off <<= 1) {
    s0 += __shfl_xor(s0, off);
    s1 += __shfl_xor(s1, off);
    s2 += __shfl_xor(s2, off);
  }
  if (lane == 0) {
    float inv = 1.0f / fmaxf((float)(end - beg), 1.0f);
    zagg[row] = make_float4(s0 * inv, s1 * inv, s2 * inv, 0.f);
  }
}

// out2: out[m][g] = zagg[m][g] + bl2[g] + m1[m] . Wr2[g]
__global__ void out2_kernel(const float4* __restrict__ zagg, const float* __restrict__ m1,
                            const float* __restrict__ Wr2, const float* __restrict__ bl2,
                            float* __restrict__ out, int n) {
  int wid = threadIdx.x >> 6, lane = threadIdx.x & 63;
  int row = blockIdx.x * 4 + wid;
  if (row >= n) return;
  float mm = m1[(size_t)row * HD + lane];
  float4 za = zagg[row];
  float zc[3] = {za.x, za.y, za.z};
#pragma unroll
  for (int g = 0; g < 3; ++g) {
    float p = mm * Wr2[g * HD + lane];
#pragma unroll
    for (int off = 32; off > 0; off >>= 1) p += __shfl_down(p, off);
    if (lane == 0) out[row * 3 + g] = p + zc[g] + bl2[g];
  }
}

// ---------------------------------------------------------------------------

extern "C" void kernel_launch(void* const* d_in, const int* in_sizes, int n_in,
                              void* d_out, int out_size, void* d_ws, size_t ws_size,
                              hipStream_t stream) {
  const float* x_user  = (const float*)d_in[0];
  const float* x_movie = (const float*)d_in[1];
  const int*   e_src   = (const int*)d_in[2];
  const int*   e_dst   = (const int*)d_in[3];
  const float* W_user  = (const float*)d_in[4];
  const float* b_user  = (const float*)d_in[5];
  const float* W_movie = (const float*)d_in[6];
  const float* b_movie = (const float*)d_in[7];
  const float* Wl1_um  = (const float*)d_in[8];
  const float* bl1_um  = (const float*)d_in[9];
  const float* Wr1_um  = (const float*)d_in[10];
  const float* Wl1_mu  = (const float*)d_in[11];
  const float* bl1_mu  = (const float*)d_in[12];
  const float* Wr1_mu  = (const float*)d_in[13];
  const float* Wl2_um  = (const float*)d_in[14];
  const float* bl2_um  = (const float*)d_in[15];
  const float* Wr2_um  = (const float*)d_in[16];
  float* outp = (float*)d_out;

  // ---- workspace carve-up ----
  char* p = (char*)d_ws;
  size_t off = 0;
  auto take = [&](size_t bytes) { void* r = p + off; off += alignup(bytes); return r; };

  int* rp_m    = (int*)take(size_t(NM + 1) * 4);
  int* rp_u    = (int*)take(size_t(NU + 1) * 4);
  int* bh      = (int*)take(size_t(NBK) * 4);
  int* bbase_m = (int*)take(size_t(MBK + 1) * 4);
  int* bbase_u = (int*)take(size_t(UBK + 1) * 4);
  int* bcur_m  = (int*)take(size_t(MBK) * 4);
  int* bcur_u  = (int*)take(size_t(UBK) * 4);
  int* csr_m   = (int*)take(size_t(NE) * 4);
  int* csr_u   = (int*)take(size_t(NE) * 4);

  // overlay: staging (build phase) aliases feature buffers (feature phase)
  size_t ov_base = off;
  unsigned* stage_m = (unsigned*)take(size_t(NE) * 4);
  unsigned* stage_u = (unsigned*)take(size_t(NE) * 4);
  size_t stage_end = off;
  off = ov_base;
  unsigned short* hu = (unsigned short*)take(size_t(NU) * HD * 2);
  unsigned short* hm = (unsigned short*)take(size_t(NM) * HD * 2);
  unsigned short* u1 = (unsigned short*)take(size_t(NU) * HD * 2);
  float* m1   = (float*)take(size_t(NM) * HD * 4);
  float* aggb = (float*)take(size_t(NU) * HD * 4);
  if (off < stage_end) off = stage_end;
  float4* z    = (float4*)take(size_t(NU) * 16);
  float4* zagg = (float4*)take(size_t(NM) * 16);
  unsigned short* Wb = (unsigned short*)take(size_t(HD) * FM * 2);
  if (off > ws_size) return;

  const int TB = 256;

  // ---- CSR build ----
  hipMemsetAsync(bh, 0, size_t(NBK) * 4, stream);
  histB_kernel<<<512, 256, 0, stream>>>(e_src, e_dst, bh);
  scanB_kernel<<<1, 1024, 0, stream>>>(bh, bbase_m, bbase_u, bcur_m, bcur_u);
  passA_kernel<<<(NE + EPB - 1) / EPB, 1024, 0, stream>>>(e_src, e_dst, bcur_m, bcur_u,
                                                          stage_m, stage_u);
  passB_kernel<<<NBK, 1024, 0, stream>>>(bbase_m, bbase_u, stage_m, stage_u,
                                         csr_m, csr_u, rp_m, rp_u);

  // ---- projections ----
  convW_kernel<<<(HD * FM + 255) / 256, 256, 0, stream>>>(W_movie, Wb, HD * FM);
  proj_user_kernel<<<NU / 16, TB, 0, stream>>>(x_user, W_user, b_user, hu);
  proj_movie_kernel<<<(NM + 63) / 64, TB, 0, stream>>>(x_movie, Wb, b_movie, hm);

  // ---- layer 1: movie side ----
  agg_mean_kernel<<<(NM + 3) / 4, TB, 0, stream>>>(hu, rp_m, csr_m, aggb, NM);
  sage64_kernel<0><<<(NM + 31) / 32, TB, 0, stream>>>(aggb, hm, Wl1_um, bl1_um, Wr1_um, m1, NM);

  // ---- layer 1: user side ----
  agg_mean_kernel<<<(NU + 3) / 4, TB, 0, stream>>>(hm, rp_u, csr_u, aggb, NU);
  sage64_kernel<1><<<(NU + 31) / 32, TB, 0, stream>>>(aggb, hu, Wl1_mu, bl1_mu, Wr1_mu, u1, NU);

  // ---- layer 2 (z-trick): project u1 -> z, aggregate z, combine ----
  zproj_kernel<<<(NU + 15) / 16, TB, 0, stream>>>(u1, Wl2_um, z);
  agg4_kernel<<<(NM + 3) / 4, TB, 0, stream>>>(z, rp_m, csr_m, zagg, NM);
  out2_kernel<<<(NM + 3) / 4, TB, 0, stream>>>(zagg, m1, Wr2_um, bl2_um, outp, NM);
}